// Round 7
// baseline (130.113 us; speedup 1.0000x reference)
//
#include <hip/hip_runtime.h>
#include <hip/hip_bf16.h>
#include <math.h>

// DecoderActor: B=16384, N=20, DM=128.
// M*sqrt(dm) = x B x^T + alpha_n + beta_m + c, B = Wn^T(Wk^T Wq)Wn,
// alpha/beta/c derived from xg = max_n x[n,:].
// Round 7: k_main with fB fragment table staged to LDS once per block
// (8 waves/block amortize the copy); F-loop B-operand now ds_read_b128
// instead of 32 interleaved L2 loads. All fragment layouts = r5/r6 verified.
#define DM 128
#define NN 20
#define NB 16384
#define BPB 8

#define OFF_A      0
#define OFF_AT     16384
#define OFF_WA     32768
#define OFF_WAT    49152
#define OFF_AG     65536
#define OFF_BMAT   81920
#define OFF_S1T    98304
#define OFF_S2T    114688
#define OFF_C2T    131072
#define OFF_U0     147456
#define OFF_V0     147584
#define OFF_T0     147712
#define OFF_W1     147840
#define OFF_AT0    147968
#define OFF_A0     148096
#define OFF_B0     148224
#define OFF_C1     148352
#define OFF_C00    148480
#define OFF_CBASE  148481
// fp16 fragment arrays (packed by k_prep4, round-2/5 verified layout)
#define OFF_FRAGB  149504            // 16384 h16 : Bmat frags (16x16x32 B-op, 8 ct)
#define OFF_FRAGS  (149504 + 8192)   // 49152 h16 : matvec S frags (16x16x32 B-op, 24 ct)
// per-batch vectors from k_abc
#define OFF_AVH    182272            // h16[16384][3][128] : avec|bvec (bias folded)
#define OFF_CW     3328000           // f32[16384] : c scalar (incl cbase)

#define INVS 0.08838834764831845f    // 1/sqrt(128)
#define FW 132                       // fFs row stride in h16

typedef _Float16 h16;
typedef h16 half8 __attribute__((ext_vector_type(8)));
typedef h16 half4v __attribute__((ext_vector_type(4)));
typedef float f32x4 __attribute__((ext_vector_type(4)));

#define MFMA16(a, b, c) __builtin_amdgcn_mfma_f32_16x16x32_f16((a), (b), (c), 0, 0, 0)

// round-2/5 verified XOR swizzle (h16 units)
__device__ __forceinline__ int swz(int row, int col) {
    return (row * 128 + col) ^ ((row & 7) << 3);
}

// ---------- prep 1: A = Wk^T Wq (and A^T), u0, v0, t0, c00 ----------
__global__ void k_prep1(const float* __restrict__ Wk, const float* __restrict__ Wq,
                        const float* __restrict__ bk, const float* __restrict__ bq,
                        const float* __restrict__ bn, const float* __restrict__ bg,
                        float* __restrict__ ws) {
    const int bx = blockIdx.x, t = threadIdx.x;
    __shared__ float sbuf[128];
    if (bx < 128) {
        sbuf[t] = Wk[t * 128 + bx];
        __syncthreads();
        float a = 0.f;
        #pragma unroll 8
        for (int d = 0; d < 128; ++d) a += sbuf[d] * Wq[d * 128 + t];
        ws[OFF_A  + bx * 128 + t] = a;
        ws[OFF_AT + t * 128 + bx] = a;
    } else {
        float u = 0.f, v = 0.f;
        #pragma unroll 8
        for (int d = 0; d < 128; ++d) {
            u += Wk[d * 128 + t] * bq[d];
            v += Wq[d * 128 + t] * bk[d];
        }
        ws[OFF_U0 + t] = u;
        ws[OFF_V0 + t] = v;
        ws[OFF_T0 + t] = bn[t] + bg[t];
        sbuf[t] = bk[t] * bq[t];
        __syncthreads();
        for (int s = 64; s > 0; s >>= 1) { if (t < s) sbuf[t] += sbuf[t + s]; __syncthreads(); }
        if (t == 0) ws[OFF_C00] = sbuf[0];
    }
}

// ---------- prep 2: WA = Wn^T A, WAT = Wn^T A^T, AG = A Wg; w1, At0, c_base ----------
__global__ void k_prep2(const float* __restrict__ Wn, const float* __restrict__ Wg,
                        float* __restrict__ ws) {
    const int bx = blockIdx.x, t = threadIdx.x;
    __shared__ float s1[128], s2[128];
    if (bx < 128) {
        const int r = bx;
        s1[t] = Wn[t * 128 + r];
        s2[t] = ws[OFF_A + r * 128 + t];
        __syncthreads();
        float wa = 0.f, wat = 0.f, ag = 0.f;
        #pragma unroll 4
        for (int e = 0; e < 128; ++e) {
            wa  += s1[e] * ws[OFF_A  + e * 128 + t];
            wat += s1[e] * ws[OFF_AT + e * 128 + t];
            ag  += s2[e] * Wg[e * 128 + t];
        }
        ws[OFF_WA  + r * 128 + t] = wa;
        ws[OFF_WAT + r * 128 + t] = wat;
        ws[OFF_AG  + r * 128 + t] = ag;
    } else {
        const float t0t = ws[OFF_T0 + t], u0t = ws[OFF_U0 + t], v0t = ws[OFF_V0 + t];
        float w1 = 0.f, at0 = 0.f;
        #pragma unroll 8
        for (int e = 0; e < 128; ++e) {
            const float t0e = ws[OFF_T0 + e];
            w1  += (ws[OFF_A + t * 128 + e] + ws[OFF_AT + t * 128 + e]) * t0e;
            at0 +=  ws[OFF_A + t * 128 + e] * t0e;
        }
        w1 += u0t + v0t;
        ws[OFF_W1  + t] = w1;
        ws[OFF_AT0 + t] = at0;
        s1[t] = t0t * (at0 + u0t + v0t);
        __syncthreads();
        for (int s = 64; s > 0; s >>= 1) { if (t < s) s1[t] += s1[t + s]; __syncthreads(); }
        if (t == 0) ws[OFF_CBASE] = s1[0] + ws[OFF_C00];
    }
}

// ---------- prep 3: Bmat, S1t, S2t, C2t; a0, b0, c1 ----------
__global__ void k_prep3(const float* __restrict__ Wn, const float* __restrict__ Wg,
                        float* __restrict__ ws) {
    const int bx = blockIdx.x, t = threadIdx.x;
    __shared__ float wa[128], wat[128], wgc[128];
    if (bx < 128) {
        const int r = bx;
        wa[t]  = ws[OFF_WA  + r * 128 + t];
        wat[t] = ws[OFF_WAT + r * 128 + t];
        wgc[t] = Wg[t * 128 + r];
        __syncthreads();
        float bm = 0.f, s1v = 0.f, s2v = 0.f, c2v = 0.f;
        #pragma unroll 4
        for (int f = 0; f < 128; ++f) {
            bm  += wa[f]  * Wn[f * 128 + t];
            s1v += wa[f]  * Wg[f * 128 + t];
            s2v += wat[f] * Wg[f * 128 + t];
            c2v += wgc[f] * ws[OFF_AG + f * 128 + t];
        }
        ws[OFF_BMAT + r * 128 + t] = bm;
        ws[OFF_S1T + t * 128 + r] = s1v;
        ws[OFF_S2T + t * 128 + r] = s2v;
        ws[OFF_C2T + t * 128 + r] = c2v;
    } else {
        float a0 = 0.f, b0 = 0.f, c1 = 0.f;
        #pragma unroll 8
        for (int f = 0; f < 128; ++f) {
            a0 += ws[OFF_WA  + t * 128 + f] * ws[OFF_T0 + f] + Wn[f * 128 + t] * ws[OFF_U0 + f];
            b0 += ws[OFF_WAT + t * 128 + f] * ws[OFF_T0 + f] + Wn[f * 128 + t] * ws[OFF_V0 + f];
            c1 += Wg[f * 128 + t] * ws[OFF_W1 + f];
        }
        ws[OFF_A0 + t] = a0;
        ws[OFF_B0 + t] = b0;
        ws[OFF_C1 + t] = c1;
    }
}

// ---------- prep 4 (verified): pack fp16 MFMA fragments, f(g,e)=8g+e ----------
__global__ void k_prep4(float* __restrict__ ws) {
    h16* fB = (h16*)(ws + OFF_FRAGB);
    h16* fS = (h16*)(ws + OFF_FRAGS);
    const int idx = blockIdx.x * 256 + threadIdx.x;     // grid covers 65536
    if (idx < 16384) {
        const int e = idx & 7, l = (idx >> 3) & 63, ks = (idx >> 9) & 3, ct = idx >> 11;
        const int k = 32 * ks + 8 * (l >> 4) + e, j = 16 * ct + (l & 15);
        fB[idx] = (h16)ws[OFF_BMAT + k * 128 + j];
    } else {
        const int sidx = idx - 16384;
        const int e = sidx & 7, l = (sidx >> 3) & 63, ks = (sidx >> 9) & 3, ct = sidx >> 11;
        const int k = 32 * ks + 8 * (l >> 4) + e, j = 16 * ct + (l & 15);
        float v;
        if (j < 128)      v = ws[OFF_S1T + k * 128 + j];
        else if (j < 256) v = ws[OFF_S2T + k * 128 + (j - 128)];
        else              v = ws[OFF_C2T + k * 128 + (j - 256)];
        fS[sidx] = (h16)v;
    }
}

// ---------- k_abc: 16 batches/block -> avec/bvec (h16) + c scalar ----------
__global__ __launch_bounds__(256) void k_abc(const float* __restrict__ x,
                                             float* __restrict__ ws) {
    __shared__ __align__(16) h16 xgl[16 * 128];   // 4 KB, swizzled
    __shared__ float cpart[16][4];
    const int t = threadIdx.x, l = t & 63, w = t >> 6;
    const int lc = l & 15, lg = l >> 4;
    const int h = l >> 5, c32 = l & 31;
    const int b0 = blockIdx.x * 16;

    // ---- xg = col-max over 20 rows, 4 batches per wave ----
    #pragma unroll
    for (int q = 0; q < 4; ++q) {
        const int bi = 4 * w + q;
        const float4* xp = (const float4*)(x + (size_t)(b0 + bi) * 2560) + c32;
        float4 mx = xp[h * 32];
        #pragma unroll
        for (int i = 1; i < 10; ++i) {
            const float4 v = xp[(2 * i + h) * 32];
            mx.x = fmaxf(mx.x, v.x); mx.y = fmaxf(mx.y, v.y);
            mx.z = fmaxf(mx.z, v.z); mx.w = fmaxf(mx.w, v.w);
        }
        mx.x = fmaxf(mx.x, __shfl_xor(mx.x, 32));
        mx.y = fmaxf(mx.y, __shfl_xor(mx.y, 32));
        mx.z = fmaxf(mx.z, __shfl_xor(mx.z, 32));
        mx.w = fmaxf(mx.w, __shfl_xor(mx.w, 32));
        if (h == 0) {
            const half4v hg = { (h16)mx.x, (h16)mx.y, (h16)mx.z, (h16)mx.w };
            *(half4v*)(xgl + swz(bi, 4 * c32)) = hg;
        }
    }
    __syncthreads();

    // ---- matvec: A-rows = 16 batches' xg; wave w owns ct = w + 4i ----
    const half8* fS = (const half8*)(ws + OFF_FRAGS);
    f32x4 sacc[6];
    #pragma unroll
    for (int i = 0; i < 6; ++i) sacc[i] = (f32x4){0.f, 0.f, 0.f, 0.f};
    #pragma unroll
    for (int ks = 0; ks < 4; ++ks) {
        const half8 ag = *(const half8*)(xgl + swz(lc, 32 * ks + 8 * lg));
        #pragma unroll
        for (int i = 0; i < 6; ++i) {
            const int ct = w + 4 * i;
            sacc[i] = MFMA16(ag, fS[(ct * 4 + ks) * 64 + l], sacc[i]);
        }
    }
    // avec/bvec (ct 0..15): C/D row = batch 4lg+r, col = 16(ct&7)+lc
    h16* avh = (h16*)(ws + OFF_AVH);
    #pragma unroll
    for (int i = 0; i < 4; ++i) {
        const int ct = w + 4 * i;
        const int v = ct >> 3, c128 = 16 * (ct & 7) + lc;
        const float bias = (v == 0) ? ws[OFF_A0 + c128] : ws[OFF_B0 + c128];
        #pragma unroll
        for (int r = 0; r < 4; ++r)
            avh[((size_t)(b0 + 4 * lg + r) * 3 + v) * 128 + c128] = (h16)(sacc[i][r] + bias);
    }
    // c partials (ct 16..23 -> j = 16w+lc, 16w+64+lc)
    float p[4] = {0.f, 0.f, 0.f, 0.f};
    #pragma unroll
    for (int i = 4; i < 6; ++i) {
        const int j = 16 * (w + 4 * i - 16) + lc;
        const float c1j = ws[OFF_C1 + j];
        #pragma unroll
        for (int r = 0; r < 4; ++r) {
            const float xgv = (float)xgl[swz(4 * lg + r, j)];
            p[r] += (sacc[i][r] + c1j) * xgv;
        }
    }
    #pragma unroll
    for (int r = 0; r < 4; ++r) {
        float v = p[r];
        v += __shfl_xor(v, 1); v += __shfl_xor(v, 2);
        v += __shfl_xor(v, 4); v += __shfl_xor(v, 8);
        if (lc == 0) cpart[4 * lg + r][w] = v;
    }
    __syncthreads();
    if (t < 16)
        ws[OFF_CW + b0 + t] = ws[OFF_CBASE]
                            + cpart[t][0] + cpart[t][1] + cpart[t][2] + cpart[t][3];
}

// ---------- k_main: one wave per batch; fB table in LDS; one barrier ----------
__global__ __launch_bounds__(512, 4) void k_main(const float* __restrict__ x,
                                                 const float* __restrict__ ws,
                                                 float* __restrict__ out) {
    __shared__ __align__(16) h16 fBl[16384];           // 32768 B: fB table (block-shared)
    __shared__ __align__(16) h16 fFs[BPB * NN * FW];   // 42240 B: wave-private F slices
    __shared__ float abL[BPB][40];                     // 1280 B
    // total 76288 B -> 2 blocks/CU x 8 waves = 16 waves/CU

    const int t = threadIdx.x, l = t & 63, w = t >> 6;
    const int lc = l & 15, lg = l >> 4;
    const int b = blockIdx.x * BPB + w;
    const half8 h8z = {};

    // ---- x fragments straight from global (L3-resident) ----
    const float* xb = x + (size_t)b * 2560;
    half8 xa0[4], xa1[4];
    #pragma unroll
    for (int ks = 0; ks < 4; ++ks) {
        const float4 v0 = *(const float4*)(xb + lc * 128 + 32 * ks + 8 * lg);
        const float4 v1 = *(const float4*)(xb + lc * 128 + 32 * ks + 8 * lg + 4);
        xa0[ks] = (half8){ (h16)v0.x, (h16)v0.y, (h16)v0.z, (h16)v0.w,
                           (h16)v1.x, (h16)v1.y, (h16)v1.z, (h16)v1.w };
    }
    #pragma unroll
    for (int ks = 0; ks < 4; ++ks) {
        half8 v = h8z;
        if (lc < 4) {
            const float4 v0 = *(const float4*)(xb + (16 + lc) * 128 + 32 * ks + 8 * lg);
            const float4 v1 = *(const float4*)(xb + (16 + lc) * 128 + 32 * ks + 8 * lg + 4);
            v = (half8){ (h16)v0.x, (h16)v0.y, (h16)v0.z, (h16)v0.w,
                         (h16)v1.x, (h16)v1.y, (h16)v1.z, (h16)v1.w };
        }
        xa1[ks] = v;
    }
    // ct8 B-operand: col0 = avec, col1 = bvec (h16 from k_abc), else 0
    const h16* avh = (const h16*)(ws + OFF_AVH);
    half8 s8[4];
    #pragma unroll
    for (int ks = 0; ks < 4; ++ks) {
        half8 v = h8z;
        if (lc < 2) v = *(const half8*)(avh + ((size_t)b * 3 + lc) * 128 + 32 * ks + 8 * lg);
        s8[ks] = v;
    }
    const float cb = ws[OFF_CW + b];

    // ---- stage fB table to LDS (linear copy, once per block) ----
    {
        const float4* src = (const float4*)(ws + OFF_FRAGB);   // 2048 float4
        float4* dst = (float4*)fBl;
        #pragma unroll
        for (int i = 0; i < 4; ++i) dst[t + 512 * i] = src[t + 512 * i];
    }
    __syncthreads();

    h16* fFw = fFs + w * NN * FW;

    // ---- F phase: F = x * B, B-op from LDS, staged to wave-private LDS ----
    #pragma unroll
    for (int ct = 0; ct < 8; ++ct) {
        f32x4 f0 = {0.f, 0.f, 0.f, 0.f}, f1 = {0.f, 0.f, 0.f, 0.f};
        #pragma unroll
        for (int ks = 0; ks < 4; ++ks) {
            const half8 bb = *(const half8*)(fBl + ((ct * 4 + ks) * 64 + l) * 8);
            f0 = MFMA16(xa0[ks], bb, f0);
            f1 = MFMA16(xa1[ks], bb, f1);
        }
        #pragma unroll
        for (int r = 0; r < 4; ++r) {
            fFw[(4 * lg + r) * FW + 16 * ct + lc] = (h16)f0[r];
            if (lg == 0) fFw[(16 + r) * FW + 16 * ct + lc] = (h16)f1[r];
        }
    }
    // ---- ct8: alpha/beta via same GEMM machinery ----
    {
        f32x4 a0c = {0.f, 0.f, 0.f, 0.f}, a1c = {0.f, 0.f, 0.f, 0.f};
        #pragma unroll
        for (int ks = 0; ks < 4; ++ks) {
            a0c = MFMA16(xa0[ks], s8[ks], a0c);
            a1c = MFMA16(xa1[ks], s8[ks], a1c);
        }
        if (lc == 0) {
            #pragma unroll
            for (int r = 0; r < 4; ++r) abL[w][4 * lg + r] = a0c[r];
            if (lg == 0) {
                #pragma unroll
                for (int r = 0; r < 4; ++r) abL[w][16 + r] = a1c[r];
            }
        }
        if (lc == 1) {
            #pragma unroll
            for (int r = 0; r < 4; ++r) abL[w][20 + 4 * lg + r] = a0c[r];
            if (lg == 0) {
                #pragma unroll
                for (int r = 0; r < 4; ++r) abL[w][36 + r] = a1c[r];
            }
        }
    }
    asm volatile("s_waitcnt lgkmcnt(0)" ::: "memory");   // private RAW fence

    // ---- M phase: M[n][m] = sum_j F[n][j] x[m][j] ----
    f32x4 mAcc[2][2];
    #pragma unroll
    for (int nt = 0; nt < 2; ++nt)
        #pragma unroll
        for (int mt = 0; mt < 2; ++mt) mAcc[nt][mt] = (f32x4){0.f, 0.f, 0.f, 0.f};
    #pragma unroll
    for (int nt = 0; nt < 2; ++nt) {
        #pragma unroll
        for (int ks = 0; ks < 4; ++ks) {
            const int row = 16 * nt + lc;
            const half8 aF = *(const half8*)(fFw + (row < NN ? row : 0) * FW + 32 * ks + 8 * lg);
            mAcc[nt][0] = MFMA16(aF, xa0[ks], mAcc[nt][0]);
            mAcc[nt][1] = MFMA16(aF, xa1[ks], mAcc[nt][1]);
        }
    }

    // ---- epilogue: + alpha/beta/c, 10*tanh, flattened softmax ----
    // fixed shift: e = exp(z-10) = exp(-20/(exp(2Mv)+1)); per-batch c shifts
    // all 400 logits equally (cancels in softmax).
    const float bm0 = abL[w][20 + lc];
    const float bm1 = (lc < 4) ? abL[w][36 + lc] : 0.f;
    float pv[2][2][4];
    float psum = 0.f;
    #pragma unroll
    for (int nt = 0; nt < 2; ++nt) {
        #pragma unroll
        for (int r = 0; r < 4; ++r) {
            const int n = 16 * nt + 4 * lg + r;
            const float an = (n < NN) ? abL[w][n] : 0.f;
            #pragma unroll
            for (int mt = 0; mt < 2; ++mt) {
                const int m = 16 * mt + lc;
                const bool valid = (n < NN) && (m < NN) && (n != m);
                const float Mv = (mAcc[nt][mt][r] + an + (mt ? bm1 : bm0) + cb) * INVS;
                const float E = __expf(2.f * Mv);
                const float e = valid ? __expf(-20.f / (E + 1.f)) : 0.f;
                pv[nt][mt][r] = e;
                psum += e;
            }
        }
    }
    #pragma unroll
    for (int off = 32; off > 0; off >>= 1) psum += __shfl_xor(psum, off);
    const float inv = 1.f / psum;

    float* ob = out + (size_t)b * 400;
    #pragma unroll
    for (int nt = 0; nt < 2; ++nt) {
        #pragma unroll
        for (int r = 0; r < 4; ++r) {
            const int n = 16 * nt + 4 * lg + r;
            if (n < NN) {
                ob[n * 20 + lc] = pv[nt][0][r] * inv;
                if (lc < 4) ob[n * 20 + 16 + lc] = pv[nt][1][r] * inv;
            }
        }
    }
}

extern "C" void kernel_launch(void* const* d_in, const int* in_sizes, int n_in,
                              void* d_out, int out_size, void* d_ws, size_t ws_size,
                              hipStream_t stream) {
    const float* x  = (const float*)d_in[0];
    const float* Wg = (const float*)d_in[1];
    const float* bg = (const float*)d_in[2];
    const float* Wn = (const float*)d_in[3];
    const float* bn = (const float*)d_in[4];
    const float* Wk = (const float*)d_in[5];
    const float* bk = (const float*)d_in[6];
    const float* Wq = (const float*)d_in[7];
    const float* bq = (const float*)d_in[8];
    float* out = (float*)d_out;
    float* ws  = (float*)d_ws;

    k_prep1<<<129, 128, 0, stream>>>(Wk, Wq, bk, bq, bn, bg, ws);
    k_prep2<<<129, 128, 0, stream>>>(Wn, Wg, ws);
    k_prep3<<<129, 128, 0, stream>>>(Wn, Wg, ws);
    k_prep4<<<256, 256, 0, stream>>>(ws);
    k_abc<<<NB / 16, 256, 0, stream>>>(x, ws);
    k_main<<<NB / BPB, 512, 0, stream>>>(x, ws, out);
}

// Round 9
// 115.173 us; speedup vs baseline: 1.1297x; 1.1297x over previous
//
#include <hip/hip_runtime.h>
#include <hip/hip_bf16.h>
#include <math.h>

// DecoderActor: B=16384, N=20, DM=128.
// M*sqrt(dm) = x B x^T + alpha_n + beta_m + c, B = Wn^T(Wk^T Wq)Wn,
// alpha/beta/c derived from xg = max_n x[n,:].
// Round 9: round-8 fused kernel with the __hmax2 header-ambiguity fixed via
// clang's __builtin_elementwise_max on a _Float16x2 ext-vector (same
// v_pk_max_f16). Single fused main kernel, x read ONCE; 4 launches total.
#define DM 128
#define NN 20
#define NB 16384
#define BPB 8

#define OFF_A      0
#define OFF_AT     16384
#define OFF_WA     32768
#define OFF_WAT    49152
#define OFF_AG     65536
#define OFF_BMAT   81920
#define OFF_S1T    98304
#define OFF_S2T    114688
#define OFF_C2T    131072
#define OFF_U0     147456
#define OFF_V0     147584
#define OFF_T0     147712
#define OFF_W1     147840
#define OFF_AT0    147968
#define OFF_A0     148096
#define OFF_B0     148224
#define OFF_C1     148352
#define OFF_C00    148480
#define OFF_CBASE  148481
// fp16 fragment arrays (packed by prep3 fold; r2/r5/r6-verified layout)
#define OFF_FRAGB  149504            // 16384 h16 : Bmat frags (16x16x32 B-op, 8 ct)
#define OFF_FRAGS  (149504 + 8192)   // 49152 h16 : matvec S frags (16x16x32 B-op, 24 ct)

#define INVS 0.08838834764831845f    // 1/sqrt(128)
#define FW 132                       // fFs row stride in h16

typedef _Float16 h16;
typedef h16 half8 __attribute__((ext_vector_type(8)));
typedef h16 half4v __attribute__((ext_vector_type(4)));
typedef h16 half2v __attribute__((ext_vector_type(2)));
typedef float f32x4 __attribute__((ext_vector_type(4)));
typedef unsigned int uint4v __attribute__((ext_vector_type(4)));

#define MFMA16(a, b, c) __builtin_amdgcn_mfma_f32_16x16x32_f16((a), (b), (c), 0, 0, 0)

// r2/r5/r6-verified XOR swizzle (h16 units)
__device__ __forceinline__ int swz(int row, int col) {
    return (row * 128 + col) ^ ((row & 7) << 3);
}

// packed f16 max via pure clang builtin (v_pk_max_f16) — no HIP header overloads
__device__ __forceinline__ unsigned pkmax(unsigned a, unsigned b) {
    const half2v r = __builtin_elementwise_max(__builtin_bit_cast(half2v, a),
                                               __builtin_bit_cast(half2v, b));
    return __builtin_bit_cast(unsigned, r);
}

// fB fragment index for value Bmat[k][j]  (h16 units)
__device__ __forceinline__ int fb_idx(int k, int j) {
    return ((j >> 4) << 11) | ((k >> 5) << 9)
         | ((((k >> 3) & 3) * 16 + (j & 15)) << 3) | (k & 7);
}

// ---------- prep 1: A = Wk^T Wq (and A^T), u0, v0, t0, c00 ----------
__global__ void k_prep1(const float* __restrict__ Wk, const float* __restrict__ Wq,
                        const float* __restrict__ bk, const float* __restrict__ bq,
                        const float* __restrict__ bn, const float* __restrict__ bg,
                        float* __restrict__ ws) {
    const int bx = blockIdx.x, t = threadIdx.x;
    __shared__ float sbuf[128];
    if (bx < 128) {
        sbuf[t] = Wk[t * 128 + bx];
        __syncthreads();
        float a = 0.f;
        #pragma unroll 8
        for (int d = 0; d < 128; ++d) a += sbuf[d] * Wq[d * 128 + t];
        ws[OFF_A  + bx * 128 + t] = a;
        ws[OFF_AT + t * 128 + bx] = a;
    } else {
        float u = 0.f, v = 0.f;
        #pragma unroll 8
        for (int d = 0; d < 128; ++d) {
            u += Wk[d * 128 + t] * bq[d];
            v += Wq[d * 128 + t] * bk[d];
        }
        ws[OFF_U0 + t] = u;
        ws[OFF_V0 + t] = v;
        ws[OFF_T0 + t] = bn[t] + bg[t];
        sbuf[t] = bk[t] * bq[t];
        __syncthreads();
        for (int s = 64; s > 0; s >>= 1) { if (t < s) sbuf[t] += sbuf[t + s]; __syncthreads(); }
        if (t == 0) ws[OFF_C00] = sbuf[0];
    }
}

// ---------- prep 2: WA = Wn^T A, WAT = Wn^T A^T, AG = A Wg; w1, At0, c_base ----------
__global__ void k_prep2(const float* __restrict__ Wn, const float* __restrict__ Wg,
                        float* __restrict__ ws) {
    const int bx = blockIdx.x, t = threadIdx.x;
    __shared__ float s1[128], s2[128];
    if (bx < 128) {
        const int r = bx;
        s1[t] = Wn[t * 128 + r];
        s2[t] = ws[OFF_A + r * 128 + t];
        __syncthreads();
        float wa = 0.f, wat = 0.f, ag = 0.f;
        #pragma unroll 4
        for (int e = 0; e < 128; ++e) {
            wa  += s1[e] * ws[OFF_A  + e * 128 + t];
            wat += s1[e] * ws[OFF_AT + e * 128 + t];
            ag  += s2[e] * Wg[e * 128 + t];
        }
        ws[OFF_WA  + r * 128 + t] = wa;
        ws[OFF_WAT + r * 128 + t] = wat;
        ws[OFF_AG  + r * 128 + t] = ag;
    } else {
        const float t0t = ws[OFF_T0 + t], u0t = ws[OFF_U0 + t], v0t = ws[OFF_V0 + t];
        float w1 = 0.f, at0 = 0.f;
        #pragma unroll 8
        for (int e = 0; e < 128; ++e) {
            const float t0e = ws[OFF_T0 + e];
            w1  += (ws[OFF_A + t * 128 + e] + ws[OFF_AT + t * 128 + e]) * t0e;
            at0 +=  ws[OFF_A + t * 128 + e] * t0e;
        }
        w1 += u0t + v0t;
        ws[OFF_W1  + t] = w1;
        ws[OFF_AT0 + t] = at0;
        s1[t] = t0t * (at0 + u0t + v0t);
        __syncthreads();
        for (int s = 64; s > 0; s >>= 1) { if (t < s) s1[t] += s1[t + s]; __syncthreads(); }
        if (t == 0) ws[OFF_CBASE] = s1[0] + ws[OFF_C00];
    }
}

// ---------- prep 3 (+pack): Bmat/S1/S2/C2 -> fragment scatter; a0, b0, c1 ----------
__global__ void k_prep3(const float* __restrict__ Wn, const float* __restrict__ Wg,
                        float* __restrict__ ws) {
    const int bx = blockIdx.x, t = threadIdx.x;
    __shared__ float wa[128], wat[128], wgc[128];
    h16* fB = (h16*)(ws + OFF_FRAGB);
    h16* fS = (h16*)(ws + OFF_FRAGS);
    if (bx < 128) {
        const int r = bx;
        wa[t]  = ws[OFF_WA  + r * 128 + t];
        wat[t] = ws[OFF_WAT + r * 128 + t];
        wgc[t] = Wg[t * 128 + r];
        __syncthreads();
        float bm = 0.f, s1v = 0.f, s2v = 0.f, c2v = 0.f;
        #pragma unroll 4
        for (int f = 0; f < 128; ++f) {
            bm  += wa[f]  * Wn[f * 128 + t];             // Bmat[r][t]
            s1v += wa[f]  * Wg[f * 128 + t];             // S1[r][t] = Scat[t][r]
            s2v += wat[f] * Wg[f * 128 + t];             // S2[r][t] = Scat[t][r+128]
            c2v += wgc[f] * ws[OFF_AG + f * 128 + t];    // C2[r][t] = Scat[t][r+256]
        }
        fB[fb_idx(r, t)]       = (h16)bm;
        fS[fb_idx(t, r)]       = (h16)s1v;
        fS[fb_idx(t, r + 128)] = (h16)s2v;
        fS[fb_idx(t, r + 256)] = (h16)c2v;
    } else {
        float a0 = 0.f, b0 = 0.f, c1 = 0.f;
        #pragma unroll 8
        for (int f = 0; f < 128; ++f) {
            a0 += ws[OFF_WA  + t * 128 + f] * ws[OFF_T0 + f] + Wn[f * 128 + t] * ws[OFF_U0 + f];
            b0 += ws[OFF_WAT + t * 128 + f] * ws[OFF_T0 + f] + Wn[f * 128 + t] * ws[OFF_V0 + f];
            c1 += Wg[f * 128 + t] * ws[OFF_W1 + f];
        }
        ws[OFF_A0 + t] = a0;
        ws[OFF_B0 + t] = b0;
        ws[OFF_C1 + t] = c1;
    }
}

// ---------- fused main: 8 waves = 8 batches; x read once ----------
__global__ __launch_bounds__(512, 6) void k_fused(const float* __restrict__ x,
                                                  const float* __restrict__ ws,
                                                  float* __restrict__ out) {
    __shared__ __align__(16) h16 xgl[BPB * 128];       // 2048 B, swizzled
    __shared__ __align__(16) h16 avhL[BPB * 2 * 128];  // 4096 B: avec|bvec (bias folded)
    __shared__ __align__(16) h16 fFs[BPB * NN * FW];   // 42240 B: wave-private F
    __shared__ float abL[BPB][40];                     // 1280 B
    __shared__ float cpart[BPB][BPB];                  // 256 B
    __shared__ float cbs[BPB];                         // 32 B
    // total ~49.9 KB -> 3 blocks/CU (24 waves/CU)

    const int t = threadIdx.x, l = t & 63, w = t >> 6;
    const int lc = l & 15, lg = l >> 4;
    const int b = blockIdx.x * BPB + w;
    const half8 h8z = {};

    // ---- load x fragments (r6-verified layout), batch = wave ----
    const float* xb = x + (size_t)b * 2560;
    half8 xa0[4], xa1[4];
    #pragma unroll
    for (int ks = 0; ks < 4; ++ks) {
        const float4 v0 = *(const float4*)(xb + lc * 128 + 32 * ks + 8 * lg);
        const float4 v1 = *(const float4*)(xb + lc * 128 + 32 * ks + 8 * lg + 4);
        xa0[ks] = (half8){ (h16)v0.x, (h16)v0.y, (h16)v0.z, (h16)v0.w,
                           (h16)v1.x, (h16)v1.y, (h16)v1.z, (h16)v1.w };
    }
    #pragma unroll
    for (int ks = 0; ks < 4; ++ks) {
        half8 v = h8z;
        if (lc < 4) {
            const float4 v0 = *(const float4*)(xb + (16 + lc) * 128 + 32 * ks + 8 * lg);
            const float4 v1 = *(const float4*)(xb + (16 + lc) * 128 + 32 * ks + 8 * lg + 4);
            v = (half8){ (h16)v0.x, (h16)v0.y, (h16)v0.z, (h16)v0.w,
                         (h16)v1.x, (h16)v1.y, (h16)v1.z, (h16)v1.w };
        }
        xa1[ks] = v;
    }

    // ---- in-register xg = col-max over 20 rows (packed h16; max commutes
    //      with monotone f16 rounding -> bit-identical to f32-max-then-cvt) ----
    #pragma unroll
    for (int ks = 0; ks < 4; ++ks) {
        uint4v m0 = __builtin_bit_cast(uint4v, xa0[ks]);
        uint4v m1 = __builtin_bit_cast(uint4v, xa1[ks]);
        #pragma unroll
        for (int s = 1; s < 16; s <<= 1) {
            #pragma unroll
            for (int wd = 0; wd < 4; ++wd)
                m0[wd] = pkmax(m0[wd], (unsigned)__shfl_xor((int)m0[wd], s));
        }
        #pragma unroll
        for (int s = 1; s < 4; s <<= 1) {
            #pragma unroll
            for (int wd = 0; wd < 4; ++wd)
                m1[wd] = pkmax(m1[wd], (unsigned)__shfl_xor((int)m1[wd], s));
        }
        #pragma unroll
        for (int wd = 0; wd < 4; ++wd) {
            const unsigned m1b = (unsigned)__shfl((int)m1[wd], l & 51); // (l&48)|(l&3)
            m0[wd] = pkmax(m0[wd], m1b);
        }
        if (lc == 0)
            *(half8*)(xgl + swz(w, 32 * ks + 8 * lg)) = __builtin_bit_cast(half8, m0);
    }
    __syncthreads();

    // ---- matvec (r6 k_abc machinery, 8 valid rows): wave w owns ct = w+8i ----
    {
        const half8* fS = (const half8*)(ws + OFF_FRAGS);
        f32x4 sacc[3];
        #pragma unroll
        for (int i = 0; i < 3; ++i) sacc[i] = (f32x4){0.f, 0.f, 0.f, 0.f};
        #pragma unroll
        for (int ks = 0; ks < 4; ++ks) {
            const half8 ag = *(const half8*)(xgl + swz(lc & 7, 32 * ks + 8 * lg));
            #pragma unroll
            for (int i = 0; i < 3; ++i) {
                const int ct = w + 8 * i;
                sacc[i] = MFMA16(ag, fS[(ct * 4 + ks) * 64 + l], sacc[i]);
            }
        }
        // avec/bvec (ct 0..15): C/D row = batch 4lg+r (rows <8 valid), col 16(ct&7)+lc
        #pragma unroll
        for (int i = 0; i < 2; ++i) {
            const int ct = w + 8 * i;
            const int v = ct >> 3, c128 = 16 * (ct & 7) + lc;
            const float bias = (v == 0) ? ws[OFF_A0 + c128] : ws[OFF_B0 + c128];
            if (lg < 2) {
                #pragma unroll
                for (int r = 0; r < 4; ++r)
                    avhL[(4 * lg + r) * 256 + v * 128 + c128] = (h16)(sacc[i][r] + bias);
            }
        }
        // c partials (ct 16+w -> j = 16w+lc)
        {
            const int j = 16 * w + lc;
            const float c1j = ws[OFF_C1 + j];
            float p[4];
            #pragma unroll
            for (int r = 0; r < 4; ++r) {
                const float xgv = (float)xgl[swz((4 * lg + r) & 7, j)];
                p[r] = (sacc[2][r] + c1j) * xgv;
            }
            #pragma unroll
            for (int r = 0; r < 4; ++r) {
                float v = p[r];
                v += __shfl_xor(v, 1); v += __shfl_xor(v, 2);
                v += __shfl_xor(v, 4); v += __shfl_xor(v, 8);
                if (lc == 0 && lg < 2) cpart[4 * lg + r][w] = v;
            }
        }
    }
    __syncthreads();
    if (t < BPB) {
        float s = ws[OFF_CBASE];
        #pragma unroll
        for (int j = 0; j < BPB; ++j) s += cpart[t][j];
        cbs[t] = s;
    }
    __syncthreads();
    // ================= fully independent per-wave from here =================

    // s8: col0 = avec, col1 = bvec (from LDS)
    half8 s8[4];
    #pragma unroll
    for (int ks = 0; ks < 4; ++ks) {
        half8 v = h8z;
        if (lc < 2) v = *(const half8*)(avhL + w * 256 + lc * 128 + 32 * ks + 8 * lg);
        s8[ks] = v;
    }
    // alpha/beta via GEMM (before F: frees s8 early)
    {
        f32x4 a0c = {0.f, 0.f, 0.f, 0.f}, a1c = {0.f, 0.f, 0.f, 0.f};
        #pragma unroll
        for (int ks = 0; ks < 4; ++ks) {
            a0c = MFMA16(xa0[ks], s8[ks], a0c);
            a1c = MFMA16(xa1[ks], s8[ks], a1c);
        }
        if (lc == 0) {
            #pragma unroll
            for (int r = 0; r < 4; ++r) abL[w][4 * lg + r] = a0c[r];
            if (lg == 0) {
                #pragma unroll
                for (int r = 0; r < 4; ++r) abL[w][16 + r] = a1c[r];
            }
        }
        if (lc == 1) {
            #pragma unroll
            for (int r = 0; r < 4; ++r) abL[w][20 + 4 * lg + r] = a0c[r];
            if (lg == 0) {
                #pragma unroll
                for (int r = 0; r < 4; ++r) abL[w][36 + r] = a1c[r];
            }
        }
    }

    h16* fFw = fFs + w * NN * FW;
    const half8* fB = (const half8*)(ws + OFF_FRAGB);

    // ---- F phase: F = x * B (B-op from L2), staged to wave-private LDS ----
    #pragma unroll
    for (int ct = 0; ct < 8; ++ct) {
        f32x4 f0 = {0.f, 0.f, 0.f, 0.f}, f1 = {0.f, 0.f, 0.f, 0.f};
        #pragma unroll
        for (int ks = 0; ks < 4; ++ks) {
            const half8 bb = fB[(ct * 4 + ks) * 64 + l];
            f0 = MFMA16(xa0[ks], bb, f0);
            f1 = MFMA16(xa1[ks], bb, f1);
        }
        #pragma unroll
        for (int r = 0; r < 4; ++r) {
            fFw[(4 * lg + r) * FW + 16 * ct + lc] = (h16)f0[r];
            if (lg == 0) fFw[(16 + r) * FW + 16 * ct + lc] = (h16)f1[r];
        }
    }
    asm volatile("s_waitcnt lgkmcnt(0)" ::: "memory");   // private RAW fence

    // ---- M phase: M[n][m] = sum_j F[n][j] x[m][j] ----
    f32x4 mAcc[2][2];
    #pragma unroll
    for (int nt = 0; nt < 2; ++nt)
        #pragma unroll
        for (int mt = 0; mt < 2; ++mt) mAcc[nt][mt] = (f32x4){0.f, 0.f, 0.f, 0.f};
    #pragma unroll
    for (int nt = 0; nt < 2; ++nt) {
        #pragma unroll
        for (int ks = 0; ks < 4; ++ks) {
            const int row = 16 * nt + lc;
            const half8 aF = *(const half8*)(fFw + (row < NN ? row : 0) * FW + 32 * ks + 8 * lg);
            mAcc[nt][0] = MFMA16(aF, xa0[ks], mAcc[nt][0]);
            mAcc[nt][1] = MFMA16(aF, xa1[ks], mAcc[nt][1]);
        }
    }

    // ---- epilogue: + alpha/beta/c, 10*tanh, flattened softmax ----
    // fixed shift: e = exp(z-10) = exp(-20/(exp(2Mv)+1))
    const float cb = cbs[w];
    const float bm0 = abL[w][20 + lc];
    const float bm1 = (lc < 4) ? abL[w][36 + lc] : 0.f;
    float pv[2][2][4];
    float psum = 0.f;
    #pragma unroll
    for (int nt = 0; nt < 2; ++nt) {
        #pragma unroll
        for (int r = 0; r < 4; ++r) {
            const int n = 16 * nt + 4 * lg + r;
            const float an = (n < NN) ? abL[w][n] : 0.f;
            #pragma unroll
            for (int mt = 0; mt < 2; ++mt) {
                const int m = 16 * mt + lc;
                const bool valid = (n < NN) && (m < NN) && (n != m);
                const float Mv = (mAcc[nt][mt][r] + an + (mt ? bm1 : bm0) + cb) * INVS;
                const float E = __expf(2.f * Mv);
                const float e = valid ? __expf(-20.f / (E + 1.f)) : 0.f;
                pv[nt][mt][r] = e;
                psum += e;
            }
        }
    }
    #pragma unroll
    for (int off = 32; off > 0; off >>= 1) psum += __shfl_xor(psum, off);
    const float inv = 1.f / psum;

    float* ob = out + (size_t)b * 400;
    #pragma unroll
    for (int nt = 0; nt < 2; ++nt) {
        #pragma unroll
        for (int r = 0; r < 4; ++r) {
            const int n = 16 * nt + 4 * lg + r;
            if (n < NN) {
                ob[n * 20 + lc] = pv[nt][0][r] * inv;
                if (lc < 4) ob[n * 20 + 16 + lc] = pv[nt][1][r] * inv;
            }
        }
    }
}

extern "C" void kernel_launch(void* const* d_in, const int* in_sizes, int n_in,
                              void* d_out, int out_size, void* d_ws, size_t ws_size,
                              hipStream_t stream) {
    const float* x  = (const float*)d_in[0];
    const float* Wg = (const float*)d_in[1];
    const float* bg = (const float*)d_in[2];
    const float* Wn = (const float*)d_in[3];
    const float* bn = (const float*)d_in[4];
    const float* Wk = (const float*)d_in[5];
    const float* bk = (const float*)d_in[6];
    const float* Wq = (const float*)d_in[7];
    const float* bq = (const float*)d_in[8];
    float* out = (float*)d_out;
    float* ws  = (float*)d_ws;

    k_prep1<<<129, 128, 0, stream>>>(Wk, Wq, bk, bq, bn, bg, ws);
    k_prep2<<<129, 128, 0, stream>>>(Wn, Wg, ws);
    k_prep3<<<129, 128, 0, stream>>>(Wn, Wg, ws);
    k_fused<<<NB / BPB, 512, 0, stream>>>(x, ws, out);
}